// Round 1
// baseline (4478.128 us; speedup 1.0000x reference)
//
#include <hip/hip_runtime.h>
#include <math.h>

// PixelQueryNet: per-cell MLP 4->64->64->64->64->3 over a 64x64 grid of cells,
// 64 pixels per cell (8x8 tile), batch 2. Weights per cell come from
// lr_params[b, c, i, j], channel stride = 64*64 = 4096 floats.
//
// Param channel map (c):
//   L0: bias [0,64)      weight [64,320)      (c = 64    + ci*64 + co, ci<4)
//   L1: bias [320,384)   weight [384,4480)    (c = 384   + ci*64 + co)
//   L2: bias [4480,4544) weight [4544,8640)   (c = 4544  + ci*64 + co)
//   L3: bias [8640,8704) weight [8704,12800)  (c = 8704  + ci*64 + co)
//   L4: bias [12800,12803) weight [12803,12995) (c = 12803 + ci*3 + co)

static constexpr int PLANE = 4096;      // 64*64 spatial plane per channel
static constexpr size_t NPAR = 12995;

__device__ __forceinline__ float leaky(float v) { return v >= 0.0f ? v : 0.01f * v; }

// One hidden 64->64 layer for this wave's cell. Activations live in LDS at
// acol[ci*256] (thread-private column); y accumulators are registers (static
// indices only). Weight loads are wave-uniform -> scalar path.
template<int BC, int WC>
__device__ __forceinline__ void hidden_layer(const float* __restrict__ wp,
                                             float* __restrict__ acol) {
  float y[64];
#pragma unroll
  for (int cog = 0; cog < 4; ++cog) {
#pragma unroll
    for (int k = 0; k < 16; ++k)
      y[cog * 16 + k] = wp[(size_t)(BC + cog * 16 + k) * PLANE];
#pragma unroll 2
    for (int ci = 0; ci < 64; ++ci) {
      float a = acol[ci * 256];
#pragma unroll
      for (int k = 0; k < 16; ++k)
        y[cog * 16 + k] =
            fmaf(a, wp[(size_t)(WC + ci * 64 + cog * 16 + k) * PLANE], y[cog * 16 + k]);
    }
  }
#pragma unroll
  for (int c = 0; c < 64; ++c)
    acol[c * 256] = leaky(y[c]);
}

__global__ __launch_bounds__(256) void pqn_kernel(const float* __restrict__ lr,
                                                  float* __restrict__ out) {
  // A[ci][tid]: activations, 64 KB. Each thread uses only its own column ->
  // no bank conflicts (lanes contiguous), no barriers needed.
  __shared__ float A[64 * 256];

  const int tid = threadIdx.x;
  const int wave = tid >> 6;
  const int lane = tid & 63;
  const int blk = blockIdx.x;
  const int b = blk >> 10;            // 1024 blocks per batch (64 i * 16 jg)
  const int i = (blk >> 4) & 63;
  const int j = __builtin_amdgcn_readfirstlane(((blk & 15) << 2) + wave);

  const float* __restrict__ wp =
      lr + (size_t)b * (NPAR * (size_t)PLANE) + (size_t)(i * 64 + j);
  float* acol = &A[tid];

  // Positional-encoding features for this lane's pixel (dy, dx in the 8x8 tile)
  const int dx = lane & 7, dy = lane >> 3;
  const float twopi = 6.28318530717958647f;
  float f0, f1, f2, f3;
  sincosf(twopi * (dx * 0.125f), &f1, &f0);  // f0 = cos, f1 = sin (x)
  sincosf(twopi * (dy * 0.125f), &f3, &f2);  // f2 = cos, f3 = sin (y)

  // Layer 0: 4 -> 64
#pragma unroll 4
  for (int co = 0; co < 64; ++co) {
    float acc = wp[(size_t)co * PLANE];
    acc = fmaf(f0, wp[(size_t)(64 + co) * PLANE], acc);
    acc = fmaf(f1, wp[(size_t)(128 + co) * PLANE], acc);
    acc = fmaf(f2, wp[(size_t)(192 + co) * PLANE], acc);
    acc = fmaf(f3, wp[(size_t)(256 + co) * PLANE], acc);
    acol[co * 256] = leaky(acc);
  }

  // Layers 1-3: 64 -> 64
  hidden_layer<320, 384>(wp, acol);
  hidden_layer<4480, 4544>(wp, acol);
  hidden_layer<8640, 8704>(wp, acol);

  // Layer 4: 64 -> 3, tanh
  float o0 = wp[(size_t)12800 * PLANE];
  float o1 = wp[(size_t)12801 * PLANE];
  float o2 = wp[(size_t)12802 * PLANE];
#pragma unroll 2
  for (int ci = 0; ci < 64; ++ci) {
    float a = acol[ci * 256];
    o0 = fmaf(a, wp[(size_t)(12803 + ci * 3) * PLANE], o0);
    o1 = fmaf(a, wp[(size_t)(12804 + ci * 3) * PLANE], o1);
    o2 = fmaf(a, wp[(size_t)(12805 + ci * 3) * PLANE], o2);
  }

  // out[b][c][i*8+dy][j*8+dx]
  const size_t obase =
      (size_t)b * 3 * 262144 + (size_t)(i * 8 + dy) * 512 + (size_t)(j * 8 + dx);
  out[obase] = tanhf(o0);
  out[obase + 262144] = tanhf(o1);
  out[obase + 524288] = tanhf(o2);
}

extern "C" void kernel_launch(void* const* d_in, const int* in_sizes, int n_in,
                              void* d_out, int out_size, void* d_ws, size_t ws_size,
                              hipStream_t stream) {
  (void)in_sizes; (void)n_in; (void)d_ws; (void)ws_size; (void)out_size;
  const float* lr = (const float*)d_in[1];  // d_in[0] = highres (unused by the math)
  float* out = (float*)d_out;
  hipLaunchKernelGGL(pqn_kernel, dim3(2048), dim3(256), 0, stream, lr, out);
}

// Round 2
// 1075.939 us; speedup vs baseline: 4.1621x; 4.1621x over previous
//
#include <hip/hip_runtime.h>
#include <math.h>

// PixelQueryNet: per-cell MLP 4->64->64->64->64->3 over a 64x64 grid of cells,
// 64 pixels (8x8) per cell, batch 2. Weights per cell come from
// lr_params[b, c, i, j] (channel stride 4096 floats = 16 KB).
//
// Two-stage: (1) transpose weights to [cell][c] contiguous vectors in d_ws,
// (2) per-cell MLP with sequential scalar weight stream.
//
// Param channel map (c):
//   L0: bias [0,64)      weight [64,320)
//   L1: bias [320,384)   weight [384,4480)
//   L2: bias [4480,4544) weight [4544,8640)
//   L3: bias [8640,8704) weight [8704,12800)
//   L4: bias [12800,12803) weight [12803,12995)

static constexpr int PLANE = 4096;       // 64*64 spatial plane per channel
static constexpr int NPAR = 12995;
static constexpr int CP = 12996;         // padded per-cell stride (x4B = 16B aligned)

__device__ __forceinline__ float leaky(float v) { return v >= 0.0f ? v : 0.01f * v; }

// ---------------- Stage 1: transpose [b,c,i,j] -> ws[cell][c] ----------------
// Block: 256 threads, handles one (b, i, 64-channel tile). LDS 64x65 tile.
__global__ __launch_bounds__(256) void transpose_kernel(const float* __restrict__ lr,
                                                        float* __restrict__ ws,
                                                        int i0, int rows) {
  __shared__ float tile[64 * 65];
  const int t = threadIdx.x;
  const int ct = blockIdx.x;           // channel tile (204 tiles)
  const int ir = blockIdx.y;           // row within chunk
  const int b = blockIdx.z;
  const int c0 = ct * 64;
  const int i = i0 + ir;

  // Read: lanes sweep j (coalesced 256B per channel row)
  {
    const int j = t & 63;
    const int lcb = t >> 6;            // wave id 0..3
#pragma unroll
    for (int r = 0; r < 16; ++r) {
      const int lc = lcb + r * 4;
      const int c = c0 + lc;
      if (c < NPAR)
        tile[lc * 65 + j] = lr[(size_t)(b * NPAR + c) * PLANE + i * 64 + j];
    }
  }
  __syncthreads();
  // Write: lanes sweep c (coalesced 256B per cell)
  {
    const int lc = t & 63;
    const int jb = t >> 6;
    const int c = c0 + lc;
    if (c < NPAR) {
#pragma unroll
      for (int r = 0; r < 16; ++r) {
        const int j = jb + r * 4;
        const size_t cell = (size_t)(b * rows + ir) * 64 + j;
        ws[cell * CP + c] = tile[lc * 65 + j];
      }
    }
  }
}

// ---------------- Stage 2: per-cell MLP, sequential weight stream ------------
template<int BC, int WC>
__device__ __forceinline__ void hidden_layer(const float* __restrict__ wp,
                                             float* __restrict__ acol) {
  float y[64];
#pragma unroll
  for (int cog = 0; cog < 4; ++cog) {
#pragma unroll
    for (int k = 0; k < 16; ++k)
      y[cog * 16 + k] = wp[BC + cog * 16 + k];
#pragma unroll 2
    for (int ci = 0; ci < 64; ++ci) {
      float a = acol[ci * 256];
#pragma unroll
      for (int k = 0; k < 16; ++k)
        y[cog * 16 + k] = fmaf(a, wp[WC + ci * 64 + cog * 16 + k], y[cog * 16 + k]);
    }
  }
#pragma unroll
  for (int c = 0; c < 64; ++c)
    acol[c * 256] = leaky(y[c]);
}

__global__ __launch_bounds__(256) void pqn_compute(const float* __restrict__ ws,
                                                   float* __restrict__ out,
                                                   int i0, int rows) {
  __shared__ float A[64 * 256];  // activations [ci][tid], thread-private columns
  const int tid = threadIdx.x;
  const int wave = tid >> 6;
  const int lane = tid & 63;
  const int jg = blockIdx.x;          // 16 groups of 4 cells
  const int ir = blockIdx.y;
  const int b = blockIdx.z;
  const int i = i0 + ir;
  const int j = __builtin_amdgcn_readfirstlane(jg * 4 + wave);

  const size_t cell = (size_t)(b * rows + ir) * 64 + j;
  const float* __restrict__ wp = ws + cell * CP;
  float* acol = &A[tid];

  const int dx = lane & 7, dy = lane >> 3;
  const float twopi = 6.28318530717958647f;
  float f0, f1, f2, f3;
  sincosf(twopi * (dx * 0.125f), &f1, &f0);
  sincosf(twopi * (dy * 0.125f), &f3, &f2);

  // Layer 0: 4 -> 64
#pragma unroll 4
  for (int co = 0; co < 64; ++co) {
    float acc = wp[co];
    acc = fmaf(f0, wp[64 + co], acc);
    acc = fmaf(f1, wp[128 + co], acc);
    acc = fmaf(f2, wp[192 + co], acc);
    acc = fmaf(f3, wp[256 + co], acc);
    acol[co * 256] = leaky(acc);
  }

  hidden_layer<320, 384>(wp, acol);
  hidden_layer<4480, 4544>(wp, acol);
  hidden_layer<8640, 8704>(wp, acol);

  // Layer 4: 64 -> 3, tanh
  float o0 = wp[12800], o1 = wp[12801], o2 = wp[12802];
#pragma unroll 2
  for (int ci = 0; ci < 64; ++ci) {
    float a = acol[ci * 256];
    o0 = fmaf(a, wp[12803 + ci * 3], o0);
    o1 = fmaf(a, wp[12804 + ci * 3], o1);
    o2 = fmaf(a, wp[12805 + ci * 3], o2);
  }

  const size_t obase =
      (size_t)b * 3 * 262144 + (size_t)(i * 8 + dy) * 512 + (size_t)(jg * 4 + wave) * 8 + dx;
  out[obase] = tanhf(o0);
  out[obase + 262144] = tanhf(o1);
  out[obase + 524288] = tanhf(o2);
}

// ---------------- Fallback (round-1 kernel, direct strided reads) ------------
template<int BC, int WC>
__device__ __forceinline__ void hidden_layer_strided(const float* __restrict__ wp,
                                                     float* __restrict__ acol) {
  float y[64];
#pragma unroll
  for (int cog = 0; cog < 4; ++cog) {
#pragma unroll
    for (int k = 0; k < 16; ++k)
      y[cog * 16 + k] = wp[(size_t)(BC + cog * 16 + k) * PLANE];
#pragma unroll 2
    for (int ci = 0; ci < 64; ++ci) {
      float a = acol[ci * 256];
#pragma unroll
      for (int k = 0; k < 16; ++k)
        y[cog * 16 + k] =
            fmaf(a, wp[(size_t)(WC + ci * 64 + cog * 16 + k) * PLANE], y[cog * 16 + k]);
    }
  }
#pragma unroll
  for (int c = 0; c < 64; ++c)
    acol[c * 256] = leaky(y[c]);
}

__global__ __launch_bounds__(256) void pqn_fallback(const float* __restrict__ lr,
                                                    float* __restrict__ out) {
  __shared__ float A[64 * 256];
  const int tid = threadIdx.x;
  const int wave = tid >> 6;
  const int lane = tid & 63;
  const int blk = blockIdx.x;
  const int b = blk >> 10;
  const int i = (blk >> 4) & 63;
  const int j = __builtin_amdgcn_readfirstlane(((blk & 15) << 2) + wave);
  const float* __restrict__ wp =
      lr + (size_t)b * ((size_t)NPAR * PLANE) + (size_t)(i * 64 + j);
  float* acol = &A[tid];
  const int dx = lane & 7, dy = lane >> 3;
  const float twopi = 6.28318530717958647f;
  float f0, f1, f2, f3;
  sincosf(twopi * (dx * 0.125f), &f1, &f0);
  sincosf(twopi * (dy * 0.125f), &f3, &f2);
#pragma unroll 4
  for (int co = 0; co < 64; ++co) {
    float acc = wp[(size_t)co * PLANE];
    acc = fmaf(f0, wp[(size_t)(64 + co) * PLANE], acc);
    acc = fmaf(f1, wp[(size_t)(128 + co) * PLANE], acc);
    acc = fmaf(f2, wp[(size_t)(192 + co) * PLANE], acc);
    acc = fmaf(f3, wp[(size_t)(256 + co) * PLANE], acc);
    acol[co * 256] = leaky(acc);
  }
  hidden_layer_strided<320, 384>(wp, acol);
  hidden_layer_strided<4480, 4544>(wp, acol);
  hidden_layer_strided<8640, 8704>(wp, acol);
  float o0 = wp[(size_t)12800 * PLANE];
  float o1 = wp[(size_t)12801 * PLANE];
  float o2 = wp[(size_t)12802 * PLANE];
#pragma unroll 2
  for (int ci = 0; ci < 64; ++ci) {
    float a = acol[ci * 256];
    o0 = fmaf(a, wp[(size_t)(12803 + ci * 3) * PLANE], o0);
    o1 = fmaf(a, wp[(size_t)(12804 + ci * 3) * PLANE], o1);
    o2 = fmaf(a, wp[(size_t)(12805 + ci * 3) * PLANE], o2);
  }
  const size_t obase =
      (size_t)b * 3 * 262144 + (size_t)(i * 8 + dy) * 512 + (size_t)(j * 8 + dx);
  out[obase] = tanhf(o0);
  out[obase + 262144] = tanhf(o1);
  out[obase + 524288] = tanhf(o2);
}

extern "C" void kernel_launch(void* const* d_in, const int* in_sizes, int n_in,
                              void* d_out, int out_size, void* d_ws, size_t ws_size,
                              hipStream_t stream) {
  (void)in_sizes; (void)n_in; (void)out_size;
  const float* lr = (const float*)d_in[1];  // d_in[0] = highres (unused by the math)
  float* out = (float*)d_out;
  float* ws = (float*)d_ws;

  // Largest power-of-2 row chunk that fits the workspace.
  int R = 0;
  for (int r = 64; r >= 1; r >>= 1) {
    if ((size_t)2 * r * 64 * CP * 4 <= ws_size) { R = r; break; }
  }
  if (R == 0) {  // workspace too small: direct strided path
    hipLaunchKernelGGL(pqn_fallback, dim3(2048), dim3(256), 0, stream, lr, out);
    return;
  }
  for (int i0 = 0; i0 < 64; i0 += R) {
    hipLaunchKernelGGL(transpose_kernel, dim3(204, R, 2), dim3(256), 0, stream,
                       lr, ws, i0, R);
    hipLaunchKernelGGL(pqn_compute, dim3(16, R, 2), dim3(256), 0, stream,
                       ws, out, i0, R);
  }
}

// Round 3
// 477.097 us; speedup vs baseline: 9.3862x; 2.2552x over previous
//
#include <hip/hip_runtime.h>
#include <math.h>

// PixelQueryNet fused kernel.
// Per low-res cell (b,i,j): MLP 4->64->64->64->64->3 (leaky 0.01, tanh) applied
// to the 64 pixels of its 8x8 tile; weights from lr_params[b,c,i,j]
// (channel stride PLANE=4096 floats).
//
// Block = 512 threads = 16 cells(j) x 8 pixel-groups(pg, 4 px each) x 4 co-blocks.
// Grid  = ph(2, px halves) x jg(4) x i(64) x b(2) = 1024 blocks; ph fastest so
// ph-pairs (which read identical weights) are dispatched adjacently -> L3 reuse.
//
// Weights streamed as 128-channel x 16-j tiles (8 KB) through a double-buffered
// LDS stage; global loads are 16B coalesced straight from the original layout.
// Activations: LDS, 64ch x 32px x 16j, bank-swizzled so all accesses are <=2-way.
//
// Channel map: L0 bias[0,64) w[64,320); hidden l: bias 320+l*4160 (64ch),
// w 384+l*4160 (4096ch); L4 bias [12800,12803) w [12803,12995).

static constexpr int PLANE = 4096;
static constexpr int NPAR  = 12995;
static constexpr int NT    = 102;   // 3 (L0) + 3*33 (hidden layers)

__device__ __forceinline__ float leaky(float v) { return v >= 0.f ? v : 0.01f * v; }

// Activation LDS index for (ci, pg, k, j); bank = j + 16*(pg&1) -> 2-way max.
__device__ __forceinline__ int aidx(int ci, int pg, int k, int j) {
  return ci * 512 + (((pg >> 1) << 2) + k) * 32 + ((pg & 1) << 4) + j;
}

__device__ __forceinline__ void tile_desc(int t, int& c0, int& nch) {
  if (t == 0)      { c0 = 0;   nch = 64;  }
  else if (t == 1) { c0 = 64;  nch = 128; }
  else if (t == 2) { c0 = 192; nch = 128; }
  else {
    int u = t - 3;
    int l = u / 33;
    int r = u - l * 33;
    if (r == 0) { c0 = 320 + l * 4160; nch = 64; }            // bias tile
    else        { c0 = 384 + l * 4160 + (r - 1) * 128; nch = 128; }
  }
}

__global__ __launch_bounds__(512) void pqn_fused(const float* __restrict__ lr,
                                                 float* __restrict__ out) {
  __shared__ float A[64 * 512];     // 128 KB activations
  __shared__ float WT[2][2048];     // 2 x 8 KB weight tiles, [c_local*16 + j]

  const int tid = threadIdx.x;
  const int j   = tid & 15;
  const int pg  = (tid >> 4) & 7;
  const int cob = tid >> 7;               // 0..3 (wave-uniform)

  const int blk = blockIdx.x;
  const int ph = blk & 1;
  const int jg = (blk >> 1) & 3;
  const int i  = (blk >> 3) & 63;
  const int b  = blk >> 9;

  const float* __restrict__ wb =
      lr + (size_t)b * NPAR * PLANE + (size_t)i * 64 + jg * 16;

  // Positional-encoding features for this thread's 4 pixels
  float fxc[4], fxs[4], fyc[4], fys[4];
#pragma unroll
  for (int k = 0; k < 4; ++k) {
    const int p = ph * 32 + pg * 4 + k;
    const int dx = p & 7, dy = p >> 3;
    const float c = 0.78539816339744830962f;  // 2*pi/8
    sincosf(c * dx, &fxs[k], &fxc[k]);
    sincosf(c * dy, &fys[k], &fyc[k]);
  }

  float y[64];                 // accumulators [co_local 0..15][k 0..3]
#pragma unroll
  for (int m = 0; m < 64; ++m) y[m] = 0.f;

  // Prologue: fetch tile 0 into regs
  float4 stg = make_float4(0.f, 0.f, 0.f, 0.f);
  {
    int c0, nch; tile_desc(0, c0, nch);
    if (tid < nch * 4)
      stg = *(const float4*)(wb + (size_t)(c0 + (tid >> 2)) * PLANE + (tid & 3) * 4);
  }

  for (int t = 0; t < NT; ++t) {
    float* buf = WT[t & 1];
    {
      int c0, nch; tile_desc(t, c0, nch);
      if (tid < nch * 4) *(float4*)&buf[tid * 4] = stg;   // waits stg's vmcnt via dep
    }
    if (t + 1 < NT) {  // issue next tile's global load; stays in flight across barriers
      int c0, nch; tile_desc(t + 1, c0, nch);
      if (tid < nch * 4)
        stg = *(const float4*)(wb + (size_t)(c0 + (tid >> 2)) * PLANE + (tid & 3) * 4);
    }
    asm volatile("s_waitcnt lgkmcnt(0)" ::: "memory");
    __builtin_amdgcn_s_barrier();
    __builtin_amdgcn_sched_barrier(0);

    // ---- compute tile t ----
    if (t == 0) {                          // L0 bias: init accumulators
#pragma unroll
      for (int co = 0; co < 16; ++co) {
        const float w = buf[(cob * 16 + co) * 16 + j];
#pragma unroll
        for (int k = 0; k < 4; ++k) y[co * 4 + k] = w;
      }
    } else if (t <= 2) {                   // L0 weights: inputs are PE features
#pragma unroll
      for (int cl = 0; cl < 2; ++cl) {
        float a0, a1, a2, a3;
        if (t == 1) {
          a0 = cl ? fxs[0] : fxc[0]; a1 = cl ? fxs[1] : fxc[1];
          a2 = cl ? fxs[2] : fxc[2]; a3 = cl ? fxs[3] : fxc[3];
        } else {
          a0 = cl ? fys[0] : fyc[0]; a1 = cl ? fys[1] : fyc[1];
          a2 = cl ? fys[2] : fyc[2]; a3 = cl ? fys[3] : fyc[3];
        }
#pragma unroll
        for (int co = 0; co < 16; ++co) {
          const float w = buf[(cl * 64 + cob * 16 + co) * 16 + j];
          y[co * 4 + 0] = fmaf(a0, w, y[co * 4 + 0]);
          y[co * 4 + 1] = fmaf(a1, w, y[co * 4 + 1]);
          y[co * 4 + 2] = fmaf(a2, w, y[co * 4 + 2]);
          y[co * 4 + 3] = fmaf(a3, w, y[co * 4 + 3]);
        }
      }
      if (t == 2) {                        // end of L0: activate, write A
        asm volatile("s_waitcnt lgkmcnt(0)" ::: "memory");
        __builtin_amdgcn_s_barrier();
        __builtin_amdgcn_sched_barrier(0);
#pragma unroll
        for (int co = 0; co < 16; ++co)
#pragma unroll
          for (int k = 0; k < 4; ++k)
            A[aidx(cob * 16 + co, pg, k, j)] = leaky(y[co * 4 + k]);
      }
    } else {
      const int u = t - 3;
      const int l = u / 33;
      const int r = u - l * 33;
      if (r == 0) {                        // hidden-layer bias: re-init accumulators
#pragma unroll
        for (int co = 0; co < 16; ++co) {
          const float w = buf[(cob * 16 + co) * 16 + j];
#pragma unroll
          for (int k = 0; k < 4; ++k) y[co * 4 + k] = w;
        }
      } else {                             // hidden-layer weights: 2 ci per tile
        const int ci0 = 2 * (r - 1);
#pragma unroll
        for (int cl = 0; cl < 2; ++cl) {
          const int ci = ci0 + cl;
          const float a0 = A[aidx(ci, pg, 0, j)];
          const float a1 = A[aidx(ci, pg, 1, j)];
          const float a2 = A[aidx(ci, pg, 2, j)];
          const float a3 = A[aidx(ci, pg, 3, j)];
#pragma unroll
          for (int co = 0; co < 16; ++co) {
            const float w = buf[(cl * 64 + cob * 16 + co) * 16 + j];
            y[co * 4 + 0] = fmaf(a0, w, y[co * 4 + 0]);
            y[co * 4 + 1] = fmaf(a1, w, y[co * 4 + 1]);
            y[co * 4 + 2] = fmaf(a2, w, y[co * 4 + 2]);
            y[co * 4 + 3] = fmaf(a3, w, y[co * 4 + 3]);
          }
        }
        if (r == 32) {                     // end of hidden layer: activate, write A
          asm volatile("s_waitcnt lgkmcnt(0)" ::: "memory");
          __builtin_amdgcn_s_barrier();    // all readers of old A done
          __builtin_amdgcn_sched_barrier(0);
#pragma unroll
          for (int co = 0; co < 16; ++co)
#pragma unroll
            for (int k = 0; k < 4; ++k)
              A[aidx(cob * 16 + co, pg, k, j)] = leaky(y[co * 4 + k]);
        }
      }
    }

    asm volatile("s_waitcnt lgkmcnt(0)" ::: "memory");
    __builtin_amdgcn_s_barrier();
    __builtin_amdgcn_sched_barrier(0);
  }

  // ---- Layer 4 (64 -> 3) + tanh epilogue ----
  float po[12];                            // partials [o][k] over this cob's ci range
#pragma unroll
  for (int m = 0; m < 12; ++m) po[m] = 0.f;
#pragma unroll
  for (int cl = 0; cl < 16; ++cl) {
    const int ci = cob * 16 + cl;
    const float a0 = A[aidx(ci, pg, 0, j)];
    const float a1 = A[aidx(ci, pg, 1, j)];
    const float a2 = A[aidx(ci, pg, 2, j)];
    const float a3 = A[aidx(ci, pg, 3, j)];
#pragma unroll
    for (int o = 0; o < 3; ++o) {
      const float w = wb[(size_t)(12803 + ci * 3 + o) * PLANE + j];
      po[o * 4 + 0] = fmaf(a0, w, po[o * 4 + 0]);
      po[o * 4 + 1] = fmaf(a1, w, po[o * 4 + 1]);
      po[o * 4 + 2] = fmaf(a2, w, po[o * 4 + 2]);
      po[o * 4 + 3] = fmaf(a3, w, po[o * 4 + 3]);
    }
  }
  __syncthreads();                         // all A reads done; reuse A for partials
  float* R = A;
#pragma unroll
  for (int m = 0; m < 12; m += 4) *(float4*)&R[tid * 12 + m] = *(float4*)&po[m];
  __syncthreads();
  if (cob == 0) {                          // tid < 128: reduce 4 partials, tanh, store
#pragma unroll
    for (int o = 0; o < 3; ++o) {
      const float bias = wb[(size_t)(12800 + o) * PLANE + j];
#pragma unroll
      for (int k = 0; k < 4; ++k) {
        float s = bias;
#pragma unroll
        for (int cb = 0; cb < 4; ++cb) s += R[(cb * 128 + tid) * 12 + o * 4 + k];
        const int p = ph * 32 + pg * 4 + k;
        const int dx = p & 7, dy = p >> 3;
        out[(size_t)b * 786432 + (size_t)o * 262144 +
            (size_t)(i * 8 + dy) * 512 + (jg * 16 + j) * 8 + dx] = tanhf(s);
      }
    }
  }
}

extern "C" void kernel_launch(void* const* d_in, const int* in_sizes, int n_in,
                              void* d_out, int out_size, void* d_ws, size_t ws_size,
                              hipStream_t stream) {
  (void)in_sizes; (void)n_in; (void)d_ws; (void)ws_size; (void)out_size;
  const float* lr = (const float*)d_in[1];  // d_in[0] = highres (unused by the math)
  float* out = (float*)d_out;
  hipLaunchKernelGGL(pqn_fused, dim3(1024), dim3(512), 0, stream, lr, out);
}

// Round 4
// 438.687 us; speedup vs baseline: 10.2080x; 1.0876x over previous
//
#include <hip/hip_runtime.h>
#include <math.h>

// PixelQueryNet fused kernel, v3.
// Per low-res cell (b,i,j): MLP 4->64->64->64->64->3 (leaky 0.01, tanh) on the
// 64 pixels of its 8x8 tile; weights from lr_params[b,c,i,j] (channel stride
// PLANE=4096 floats).
//
// Block = 256 threads = 8 cells(j) x 8 pixel-rows(pg) x 4 co-blocks(cob);
// each thread owns y[16 co][8 px] accumulators (static -> registers).
// Grid = 1024; blocks n and n+8 (same XCD under n%8 round-robin) take the
// even/odd jg halves of each 64B weight line -> L2 sharing.
//
// Weight tiles (<=128 ch x 8 j) double-buffered in LDS layout [j][132] so
// weight reads are ds_read_b128 with ~128B distinct/wave-inst (conflict-free).
// One raw s_barrier + lgkmcnt(0) per tile; global prefetch (2-deep, named
// stgA/stgB) stays in flight across barriers (counted vmcnt by compiler).
//
// Channel map: L0 bias[0,64) w[64,320); hidden l: bias 320+l*4160,
// w 384+l*4160+...; L4 bias [12800,12803) w [12803,12995).

static constexpr int PLANE = 4096;
static constexpr int NPAR  = 12995;
static constexpr int NT    = 102;   // 3 (L0) + 3*33 (hidden)
static constexpr int WROW  = 132;   // words per j-row in weight buf (pad: 4j banks)
static constexpr int A_CI  = 544;   // words per ci slice; addr = ci*544 + pg*68 + j*8 + k

__device__ __forceinline__ float leaky(float v) { return fmaxf(v, 0.01f * v); }

__device__ __forceinline__ void tile_desc(int t, int& c0, int& nch, int& ci0,
                                          int& type, bool& fl) {
  // type: 0=bias(init y), 1=L0 x-features, 2=L0 y-features, 3=hidden weights
  if (t == 0)      { c0 = 0;   nch = 64;  ci0 = 0; type = 0; fl = false; }
  else if (t == 1) { c0 = 64;  nch = 128; ci0 = 0; type = 1; fl = false; }
  else if (t == 2) { c0 = 192; nch = 128; ci0 = 2; type = 2; fl = true; }
  else {
    const int u = t - 3, l = u / 33, r = u - l * 33;
    if (r == 0) { c0 = 320 + l * 4160; nch = 64; ci0 = 0; type = 0; fl = false; }
    else {
      c0 = 384 + l * 4160 + (r - 1) * 128; nch = 128; ci0 = (r - 1) * 2;
      type = 3; fl = (r == 32);
    }
  }
}

__global__ __launch_bounds__(256, 1) void pqn(const float* __restrict__ lr,
                                              float* __restrict__ out) {
  __shared__ alignas(16) float A[64 * A_CI];     // 139264 B activations
  __shared__ alignas(16) float WB[2][8 * WROW];  // 2 x 4224 B weight tiles

  const int tid = threadIdx.x;
  const int j   = tid & 7;
  const int pg  = (tid >> 3) & 7;       // pixel row (dy)
  const int cob = tid >> 6;             // wave id = co block

  // ---- block swizzle: (n, n+8) same XCD, even/odd jg halves of weight lines
  const int n = blockIdx.x;
  const int e = (n >> 3) & 1;
  const int P = (n & 7) | ((n >> 4) << 3);   // 0..511
  const int jg = ((P & 3) << 1) | e;
  const int i  = (P >> 2) & 63;
  const int b  = (P >> 8) & 1;

  const float* __restrict__ wb =
      lr + (size_t)b * NPAR * PLANE + (size_t)(i * 64 + jg * 8);

  // ---- PE features: dx = k (0..7), dy = pg
  float fxc[8], fxs[8];
#pragma unroll
  for (int k = 0; k < 8; ++k)
    sincosf(0.78539816339744830962f * k, &fxs[k], &fxc[k]);
  float fyc, fys;
  sincosf(0.78539816339744830962f * pg, &fys, &fyc);

  const int sc = tid >> 1;             // staging channel 0..127
  const int sj = (tid & 1) * 4;        // staging j-quad
  const int wbase = j * 33 + cob * 4;  // float4 index into weight row
  const int abase = pg * 68 + j * 8;   // word offset within ci slice

  float y[128];                        // [co_local 0..15][k 0..7]

  auto compute = [&](int t, int buf) {
    int c0, nch, ci0, type; bool fl;
    tile_desc(t, c0, nch, ci0, type, fl);
    const float4* W4 = (const float4*)WB[buf];
    if (type == 0) {                       // bias: init accumulators
#pragma unroll
      for (int q = 0; q < 4; ++q) {
        const float4 w = W4[wbase + q];
#pragma unroll
        for (int m = 0; m < 4; ++m) {
          const float v = ((const float*)&w)[m];
#pragma unroll
          for (int k = 0; k < 8; ++k) y[(q * 4 + m) * 8 + k] = v;
        }
      }
    } else if (type != 3) {                // L0 feature tiles
#pragma unroll
      for (int cl = 0; cl < 2; ++cl) {
#pragma unroll
        for (int q = 0; q < 4; ++q) {
          const float4 w = W4[wbase + cl * 16 + q];
#pragma unroll
          for (int m = 0; m < 4; ++m) {
            const float wv = ((const float*)&w)[m];
            const int co = q * 4 + m;
            if (type == 1) {
#pragma unroll
              for (int k = 0; k < 8; ++k)
                y[co * 8 + k] = fmaf(cl ? fxs[k] : fxc[k], wv, y[co * 8 + k]);
            } else {
              const float a = cl ? fys : fyc;
#pragma unroll
              for (int k = 0; k < 8; ++k)
                y[co * 8 + k] = fmaf(a, wv, y[co * 8 + k]);
            }
          }
        }
      }
    } else {                               // hidden weights: 2 ci per tile
#pragma unroll
      for (int cl = 0; cl < 2; ++cl) {
        const int ci = ci0 + cl;
        const float4 a0 = *(const float4*)&A[ci * A_CI + abase];
        const float4 a1 = *(const float4*)&A[ci * A_CI + abase + 4];
        const float av[8] = {a0.x, a0.y, a0.z, a0.w, a1.x, a1.y, a1.z, a1.w};
#pragma unroll
        for (int q = 0; q < 4; ++q) {
          const float4 w = W4[wbase + cl * 16 + q];
#pragma unroll
          for (int m = 0; m < 4; ++m) {
            const float wv = ((const float*)&w)[m];
            const int co = q * 4 + m;
#pragma unroll
            for (int k = 0; k < 8; ++k)
              y[co * 8 + k] = fmaf(av[k], wv, y[co * 8 + k]);
          }
        }
      }
    }
    if (fl) {                              // layer end: publish activations
      asm volatile("s_waitcnt lgkmcnt(0)" ::: "memory");  // own A-reads done
      __builtin_amdgcn_s_barrier();                       // everyone's reads done
      __builtin_amdgcn_sched_barrier(0);
#pragma unroll
      for (int co = 0; co < 16; ++co) {
        float4 v0, v1;
        v0.x = leaky(y[co * 8 + 0]); v0.y = leaky(y[co * 8 + 1]);
        v0.z = leaky(y[co * 8 + 2]); v0.w = leaky(y[co * 8 + 3]);
        v1.x = leaky(y[co * 8 + 4]); v1.y = leaky(y[co * 8 + 5]);
        v1.z = leaky(y[co * 8 + 6]); v1.w = leaky(y[co * 8 + 7]);
        *(float4*)&A[(cob * 16 + co) * A_CI + abase] = v0;
        *(float4*)&A[(cob * 16 + co) * A_CI + abase + 4] = v1;
      }
    }
  };

  // ---- prologue: 2-deep prefetch
  float4 stgA = {}, stgB = {};
  {
    int c0, nch, ci0, type; bool fl;
    tile_desc(0, c0, nch, ci0, type, fl);
    if (sc < nch) stgA = *(const float4*)(wb + (size_t)(c0 + sc) * PLANE + sj);
    tile_desc(1, c0, nch, ci0, type, fl);
    if (sc < nch) stgB = *(const float4*)(wb + (size_t)(c0 + sc) * PLANE + sj);
  }

  for (int t = 0; t < NT; t += 2) {
    // ---- phase A: tile t -> buf 0
    {
      int c0, nch, ci0, type; bool fl; tile_desc(t, c0, nch, ci0, type, fl);
      if (sc < nch) {
#pragma unroll
        for (int k = 0; k < 4; ++k)
          WB[0][(sj + k) * WROW + sc] = ((const float*)&stgA)[k];
      }
    }
    asm volatile("s_waitcnt lgkmcnt(0)" ::: "memory");
    __builtin_amdgcn_s_barrier();
    __builtin_amdgcn_sched_barrier(0);
    if (t + 2 < NT) {
      int c0, nch, ci0, type; bool fl; tile_desc(t + 2, c0, nch, ci0, type, fl);
      if (sc < nch) stgA = *(const float4*)(wb + (size_t)(c0 + sc) * PLANE + sj);
    }
    compute(t, 0);
    // ---- phase B: tile t+1 -> buf 1
    {
      int c0, nch, ci0, type; bool fl; tile_desc(t + 1, c0, nch, ci0, type, fl);
      if (sc < nch) {
#pragma unroll
        for (int k = 0; k < 4; ++k)
          WB[1][(sj + k) * WROW + sc] = ((const float*)&stgB)[k];
      }
    }
    asm volatile("s_waitcnt lgkmcnt(0)" ::: "memory");
    __builtin_amdgcn_s_barrier();
    __builtin_amdgcn_sched_barrier(0);
    if (t + 3 < NT) {
      int c0, nch, ci0, type; bool fl; tile_desc(t + 3, c0, nch, ci0, type, fl);
      if (sc < nch) stgB = *(const float4*)(wb + (size_t)(c0 + sc) * PLANE + sj);
    }
    compute(t + 1, 1);
  }

  // ---- epilogue: L4 (64 -> 3) + tanh
  asm volatile("s_waitcnt lgkmcnt(0)" ::: "memory");
  __builtin_amdgcn_s_barrier();
  __builtin_amdgcn_sched_barrier(0);

  float po[24];
#pragma unroll
  for (int m = 0; m < 24; ++m) po[m] = 0.f;
#pragma unroll
  for (int cl = 0; cl < 16; ++cl) {
    const int ci = cob * 16 + cl;
    const float4 a0 = *(const float4*)&A[ci * A_CI + abase];
    const float4 a1 = *(const float4*)&A[ci * A_CI + abase + 4];
    const float av[8] = {a0.x, a0.y, a0.z, a0.w, a1.x, a1.y, a1.z, a1.w};
#pragma unroll
    for (int o = 0; o < 3; ++o) {
      const float w = wb[(size_t)(12803 + ci * 3 + o) * PLANE + j];
#pragma unroll
      for (int k = 0; k < 8; ++k)
        po[o * 8 + k] = fmaf(av[k], w, po[o * 8 + k]);
    }
  }
  asm volatile("s_waitcnt lgkmcnt(0)" ::: "memory");
  __builtin_amdgcn_s_barrier();          // all A reads done -> reuse A
  float* R = A;
#pragma unroll
  for (int m = 0; m < 24; m += 4)
    *(float4*)&R[tid * 24 + m] = *(float4*)&po[m];
  asm volatile("s_waitcnt lgkmcnt(0)" ::: "memory");
  __builtin_amdgcn_s_barrier();
  __builtin_amdgcn_sched_barrier(0);

  if (cob == 0) {                        // tid < 64: one (j, pg) per thread
#pragma unroll
    for (int o = 0; o < 3; ++o) {
      const float bias = wb[(size_t)(12800 + o) * PLANE + j];
      float s[8];
#pragma unroll
      for (int k = 0; k < 8; ++k) s[k] = bias;
#pragma unroll
      for (int cb = 0; cb < 4; ++cb) {
#pragma unroll
        for (int k = 0; k < 8; ++k)
          s[k] += R[(cb * 64 + tid) * 24 + o * 8 + k];
      }
      float4 v0, v1;
      v0.x = tanhf(s[0]); v0.y = tanhf(s[1]); v0.z = tanhf(s[2]); v0.w = tanhf(s[3]);
      v1.x = tanhf(s[4]); v1.y = tanhf(s[5]); v1.z = tanhf(s[6]); v1.w = tanhf(s[7]);
      float* op = out + (size_t)b * 786432 + (size_t)o * 262144 +
                  (size_t)(i * 8 + pg) * 512 + (size_t)((jg * 8 + j) * 8);
      *(float4*)op = v0;
      *(float4*)(op + 4) = v1;
    }
  }
}

extern "C" void kernel_launch(void* const* d_in, const int* in_sizes, int n_in,
                              void* d_out, int out_size, void* d_ws, size_t ws_size,
                              hipStream_t stream) {
  (void)in_sizes; (void)n_in; (void)d_ws; (void)ws_size; (void)out_size;
  const float* lr = (const float*)d_in[1];  // d_in[0] = highres (unused by the math)
  float* out = (float*)d_out;
  hipLaunchKernelGGL(pqn, dim3(1024), dim3(256), 0, stream, lr, out);
}

// Round 5
// 371.164 us; speedup vs baseline: 12.0651x; 1.1819x over previous
//
#include <hip/hip_runtime.h>
#include <math.h>

// PixelQueryNet fused kernel, v4.
// Per low-res cell (b,i,j): MLP 4->64->64->64->64->3 (leaky 0.01, tanh) on the
// 64 pixels of its 8x8 tile; weights from lr_params[b,c,i,j] (channel stride
// PLANE=4096 floats).
//
// Block = 256 threads = 4 cells(j) x 8 pixel-rows(pg) x 8 co-blocks(cob);
// each thread owns y[8 co][8 px] (static -> registers). LDS ~76 KB ->
// 2 blocks/CU (8 waves/CU, 2/SIMD) so blocks mutually hide latency.
// Grid = 2048; siblings n,n+8,n+16,n+24 (same XCD under %8 round-robin) take
// the four 16B j-quads of each 64B weight line -> L2 sharing, HBM stays ideal.
//
// Weight tiles (<=128ch x 4j) double-buffered in LDS [j][132]; A activations
// at ci*288 + pg*36 + j*8 + k (padded strides -> bank-conflict floor).
// One raw s_barrier + lgkmcnt(0) per tile; 2-deep global prefetch stays in
// flight across barriers.

static constexpr int PLANE = 4096;
static constexpr int NPAR  = 12995;
static constexpr int NT    = 102;   // 3 (L0) + 3*33 (hidden)
static constexpr int WROW  = 132;   // words per j-row in weight tile
static constexpr int A_CI  = 288;   // words per ci slice: pg*36 + j*8 + k

__device__ __forceinline__ float leaky(float v) { return fmaxf(v, 0.01f * v); }

// PE x-features are compile-time: cos/sin(2*pi*k/8), k = dx.
__device__ __forceinline__ constexpr float cx(int k) {
  constexpr float R = 0.70710678118654752f;
  const float t[8] = {1.f, R, 0.f, -R, -1.f, -R, 0.f, R};
  return t[k];
}
__device__ __forceinline__ constexpr float sx(int k) {
  constexpr float R = 0.70710678118654752f;
  const float t[8] = {0.f, R, 1.f, R, 0.f, -R, -1.f, -R};
  return t[k];
}

__device__ __forceinline__ void tile_desc(int t, int& c0, int& nch, int& ci0,
                                          int& type, bool& fl) {
  // type: 0=bias(init y), 1=L0 x-features, 2=L0 y-features, 3=hidden weights
  if (t == 0)      { c0 = 0;   nch = 64;  ci0 = 0; type = 0; fl = false; }
  else if (t == 1) { c0 = 64;  nch = 128; ci0 = 0; type = 1; fl = false; }
  else if (t == 2) { c0 = 192; nch = 128; ci0 = 2; type = 2; fl = true; }
  else {
    const int u = t - 3, l = u / 33, r = u - l * 33;
    if (r == 0) { c0 = 320 + l * 4160; nch = 64; ci0 = 0; type = 0; fl = false; }
    else {
      c0 = 384 + l * 4160 + (r - 1) * 128; nch = 128; ci0 = (r - 1) * 2;
      type = 3; fl = (r == 32);
    }
  }
}

__global__ __launch_bounds__(256, 2) void pqn(const float* __restrict__ lr,
                                              float* __restrict__ out) {
  __shared__ alignas(16) float A[64 * A_CI];      // 73728 B
  __shared__ alignas(16) float WB[2][4 * WROW];   // 4224 B

  const int tid = threadIdx.x;
  const int j   = tid & 3;
  const int pg  = (tid >> 2) & 7;      // pixel row (dy)
  const int cob = tid >> 5;            // 0..7

  // ---- swizzle: 4 siblings (same XCD) cover one 64B weight line
  const int n  = blockIdx.x;
  const int e2 = (n >> 3) & 3;
  const int P  = (n & 7) | ((n >> 5) << 3);   // 0..511
  const int jg = ((P & 3) << 2) | e2;         // 0..15 (4-j group)
  const int i  = (P >> 2) & 63;
  const int b  = (P >> 8) & 1;

  const float* __restrict__ wb =
      lr + (size_t)b * NPAR * PLANE + (size_t)(i * 64 + jg * 4);

  float fyc, fys;
  sincosf(0.78539816339744830962f * pg, &fys, &fyc);

  const int abase = pg * 36 + j * 8;
  const int wrow  = j * WROW;

  float y[64];                         // [col 0..7][k 0..7]

  auto compute = [&](int t, int bufsel) {
    int c0, nch, ci0, type; bool fl;
    tile_desc(t, c0, nch, ci0, type, fl);
    const float* Wt = WB[bufsel];
    if (type == 0) {                   // bias: init accumulators
#pragma unroll
      for (int q = 0; q < 2; ++q) {
        const float4 w = *(const float4*)&Wt[wrow + cob * 8 + q * 4];
#pragma unroll
        for (int m = 0; m < 4; ++m) {
          const float v = ((const float*)&w)[m];
#pragma unroll
          for (int k = 0; k < 8; ++k) y[(q * 4 + m) * 8 + k] = v;
        }
      }
    } else if (type == 1) {            // L0 x-features (compile-time a)
#pragma unroll
      for (int cl = 0; cl < 2; ++cl) {
#pragma unroll
        for (int q = 0; q < 2; ++q) {
          const float4 w = *(const float4*)&Wt[wrow + cl * 64 + cob * 8 + q * 4];
#pragma unroll
          for (int m = 0; m < 4; ++m) {
            const float wv = ((const float*)&w)[m];
            const int col = q * 4 + m;
#pragma unroll
            for (int k = 0; k < 8; ++k)
              y[col * 8 + k] = fmaf(cl ? sx(k) : cx(k), wv, y[col * 8 + k]);
          }
        }
      }
    } else if (type == 2) {            // L0 y-features (uniform over k)
#pragma unroll
      for (int cl = 0; cl < 2; ++cl) {
        const float a = cl ? fys : fyc;
#pragma unroll
        for (int q = 0; q < 2; ++q) {
          const float4 w = *(const float4*)&Wt[wrow + cl * 64 + cob * 8 + q * 4];
#pragma unroll
          for (int m = 0; m < 4; ++m) {
            const float wv = ((const float*)&w)[m];
            const int col = q * 4 + m;
#pragma unroll
            for (int k = 0; k < 8; ++k)
              y[col * 8 + k] = fmaf(a, wv, y[col * 8 + k]);
          }
        }
      }
    } else {                           // hidden: 2 ci per tile
#pragma unroll
      for (int cl = 0; cl < 2; ++cl) {
        const int ci = ci0 + cl;
        const float4 a0 = *(const float4*)&A[ci * A_CI + abase];
        const float4 a1 = *(const float4*)&A[ci * A_CI + abase + 4];
#pragma unroll
        for (int q = 0; q < 2; ++q) {
          const float4 w = *(const float4*)&Wt[wrow + cl * 64 + cob * 8 + q * 4];
#pragma unroll
          for (int m = 0; m < 4; ++m) {
            const float wv = ((const float*)&w)[m];
            const int col = q * 4 + m;
            y[col * 8 + 0] = fmaf(a0.x, wv, y[col * 8 + 0]);
            y[col * 8 + 1] = fmaf(a0.y, wv, y[col * 8 + 1]);
            y[col * 8 + 2] = fmaf(a0.z, wv, y[col * 8 + 2]);
            y[col * 8 + 3] = fmaf(a0.w, wv, y[col * 8 + 3]);
            y[col * 8 + 4] = fmaf(a1.x, wv, y[col * 8 + 4]);
            y[col * 8 + 5] = fmaf(a1.y, wv, y[col * 8 + 5]);
            y[col * 8 + 6] = fmaf(a1.z, wv, y[col * 8 + 6]);
            y[col * 8 + 7] = fmaf(a1.w, wv, y[col * 8 + 7]);
          }
        }
      }
    }
    if (fl) {                          // layer end: publish activations
      asm volatile("s_waitcnt lgkmcnt(0)" ::: "memory");
      __builtin_amdgcn_s_barrier();    // everyone's A-reads done
      __builtin_amdgcn_sched_barrier(0);
#pragma unroll
      for (int col = 0; col < 8; ++col) {
        float4 v0, v1;
        v0.x = leaky(y[col * 8 + 0]); v0.y = leaky(y[col * 8 + 1]);
        v0.z = leaky(y[col * 8 + 2]); v0.w = leaky(y[col * 8 + 3]);
        v1.x = leaky(y[col * 8 + 4]); v1.y = leaky(y[col * 8 + 5]);
        v1.z = leaky(y[col * 8 + 6]); v1.w = leaky(y[col * 8 + 7]);
        *(float4*)&A[(cob * 8 + col) * A_CI + abase] = v0;
        *(float4*)&A[(cob * 8 + col) * A_CI + abase + 4] = v1;
      }
    }
  };

  // ---- prologue: 2-deep prefetch
  float4 stgA = {}, stgB = {};
  {
    int c0, nch, ci0, type; bool fl;
    tile_desc(0, c0, nch, ci0, type, fl);
    if (tid < nch) stgA = *(const float4*)(wb + (size_t)(c0 + tid) * PLANE);
    tile_desc(1, c0, nch, ci0, type, fl);
    if (tid < nch) stgB = *(const float4*)(wb + (size_t)(c0 + tid) * PLANE);
  }

  for (int t = 0; t < NT; t += 2) {
    // ---- phase A: tile t -> buf 0
    {
      int c0, nch, ci0, type; bool fl; tile_desc(t, c0, nch, ci0, type, fl);
      if (tid < nch) {
#pragma unroll
        for (int jj = 0; jj < 4; ++jj)
          WB[0][jj * WROW + tid] = ((const float*)&stgA)[jj];
      }
    }
    asm volatile("s_waitcnt lgkmcnt(0)" ::: "memory");
    __builtin_amdgcn_s_barrier();
    __builtin_amdgcn_sched_barrier(0);
    if (t + 2 < NT) {
      int c0, nch, ci0, type; bool fl; tile_desc(t + 2, c0, nch, ci0, type, fl);
      if (tid < nch) stgA = *(const float4*)(wb + (size_t)(c0 + tid) * PLANE);
    }
    compute(t, 0);
    // ---- phase B: tile t+1 -> buf 1
    {
      int c0, nch, ci0, type; bool fl; tile_desc(t + 1, c0, nch, ci0, type, fl);
      if (tid < nch) {
#pragma unroll
        for (int jj = 0; jj < 4; ++jj)
          WB[1][jj * WROW + tid] = ((const float*)&stgB)[jj];
      }
    }
    asm volatile("s_waitcnt lgkmcnt(0)" ::: "memory");
    __builtin_amdgcn_s_barrier();
    __builtin_amdgcn_sched_barrier(0);
    if (t + 3 < NT) {
      int c0, nch, ci0, type; bool fl; tile_desc(t + 3, c0, nch, ci0, type, fl);
      if (tid < nch) stgB = *(const float4*)(wb + (size_t)(c0 + tid) * PLANE);
    }
    compute(t + 1, 1);
  }

  // ---- epilogue: L4 (64 -> 3) + tanh
  asm volatile("s_waitcnt lgkmcnt(0)" ::: "memory");
  __builtin_amdgcn_s_barrier();
  __builtin_amdgcn_sched_barrier(0);

  float po[24];
#pragma unroll
  for (int m = 0; m < 24; ++m) po[m] = 0.f;
#pragma unroll
  for (int cl = 0; cl < 8; ++cl) {
    const int ci = cob * 8 + cl;
    const float4 a0 = *(const float4*)&A[ci * A_CI + abase];
    const float4 a1 = *(const float4*)&A[ci * A_CI + abase + 4];
#pragma unroll
    for (int o = 0; o < 3; ++o) {
      const float w = wb[(size_t)(12803 + ci * 3 + o) * PLANE + j];
      po[o * 8 + 0] = fmaf(a0.x, w, po[o * 8 + 0]);
      po[o * 8 + 1] = fmaf(a0.y, w, po[o * 8 + 1]);
      po[o * 8 + 2] = fmaf(a0.z, w, po[o * 8 + 2]);
      po[o * 8 + 3] = fmaf(a0.w, w, po[o * 8 + 3]);
      po[o * 8 + 4] = fmaf(a1.x, w, po[o * 8 + 4]);
      po[o * 8 + 5] = fmaf(a1.y, w, po[o * 8 + 5]);
      po[o * 8 + 6] = fmaf(a1.z, w, po[o * 8 + 6]);
      po[o * 8 + 7] = fmaf(a1.w, w, po[o * 8 + 7]);
    }
  }
  asm volatile("s_waitcnt lgkmcnt(0)" ::: "memory");
  __builtin_amdgcn_s_barrier();        // all A reads done -> reuse A
  float* R = A;
#pragma unroll
  for (int m = 0; m < 24; m += 4)
    *(float4*)&R[tid * 24 + m] = *(float4*)&po[m];
  asm volatile("s_waitcnt lgkmcnt(0)" ::: "memory");
  __builtin_amdgcn_s_barrier();
  __builtin_amdgcn_sched_barrier(0);

  if (cob == 0) {                      // tid < 32: one (j, pg) per thread
#pragma unroll
    for (int o = 0; o < 3; ++o) {
      const float bias = wb[(size_t)(12800 + o) * PLANE + j];
      float s[8];
#pragma unroll
      for (int k = 0; k < 8; ++k) s[k] = bias;
#pragma unroll
      for (int cb = 0; cb < 8; ++cb) {
#pragma unroll
        for (int k = 0; k < 8; ++k)
          s[k] += R[(cb * 32 + tid) * 24 + o * 8 + k];
      }
      float4 v0, v1;
      v0.x = tanhf(s[0]); v0.y = tanhf(s[1]); v0.z = tanhf(s[2]); v0.w = tanhf(s[3]);
      v1.x = tanhf(s[4]); v1.y = tanhf(s[5]); v1.z = tanhf(s[6]); v1.w = tanhf(s[7]);
      float* op = out + (size_t)b * 786432 + (size_t)o * 262144 +
                  (size_t)(i * 8 + pg) * 512 + (size_t)((jg * 4 + j) * 8);
      *(float4*)op = v0;
      *(float4*)(op + 4) = v1;
    }
  }
}

extern "C" void kernel_launch(void* const* d_in, const int* in_sizes, int n_in,
                              void* d_out, int out_size, void* d_ws, size_t ws_size,
                              hipStream_t stream) {
  (void)in_sizes; (void)n_in; (void)d_ws; (void)ws_size; (void)out_size;
  const float* lr = (const float*)d_in[1];  // d_in[0] = highres (unused by the math)
  float* out = (float*)d_out;
  hipLaunchKernelGGL(pqn, dim3(2048), dim3(256), 0, stream, lr, out);
}

// Round 6
// 370.049 us; speedup vs baseline: 12.1014x; 1.0030x over previous
//
#include <hip/hip_runtime.h>
#include <math.h>

// PixelQueryNet fused kernel, v5.
// Per low-res cell (b,i,j): MLP 4->64->64->64->64->3 (leaky 0.01, tanh) on the
// 64 pixels of its 8x8 tile; weights from lr_params[b,c,i,j] (channel stride
// PLANE=4096 floats).
//
// Block = 256 threads = 4 cells(j) x 8 pixel-rows(pg) x 8 co-blocks(cob);
// y[8co][8px] accumulators in registers. ~70 KB LDS -> 2 blocks/CU.
// Grid = 2048; siblings n,n+8,n+16,n+24 (same XCD under %8 round-robin) take
// the four 16B j-quads of each 64B weight line -> L2 sharing, HBM ideal.
//
// Activations: two unpadded planes A_lo/A_hi (k0..3 / k4..7), word addr
// ci*128 + pg*16 + j*4  == ci*128 + (lane&31)*4  -> every ds_read/write_b128
// is lane-contiguous (conflict-free by construction; fixes R5's 7.7e7
// SQ_LDS_BANK_CONFLICT from the pg*36-padded layout).
// Weight tiles [j][132] double-buffered; reads are <=4 distinct quads/phase.
// One raw s_barrier + lgkmcnt(0) per tile; 2-deep global prefetch stays in
// flight across barriers (counted vmcnt via register dependency).

static constexpr int PLANE = 4096;
static constexpr int NPAR  = 12995;
static constexpr int NT    = 102;   // 3 (L0) + 3*33 (hidden)
static constexpr int WROW  = 132;   // words per j-row in weight tile
static constexpr int AHI   = 8192;  // word offset of the k4..7 plane

__device__ __forceinline__ float leaky(float v) { return fmaxf(v, 0.01f * v); }

// PE x-features are compile-time: cos/sin(2*pi*k/8), k = dx.
__device__ __forceinline__ constexpr float cx(int k) {
  constexpr float R = 0.70710678118654752f;
  const float t[8] = {1.f, R, 0.f, -R, -1.f, -R, 0.f, R};
  return t[k];
}
__device__ __forceinline__ constexpr float sx(int k) {
  constexpr float R = 0.70710678118654752f;
  const float t[8] = {0.f, R, 1.f, R, 0.f, -R, -1.f, -R};
  return t[k];
}

__device__ __forceinline__ void tile_desc(int t, int& c0, int& nch, int& ci0,
                                          int& type, bool& fl) {
  // type: 0=bias(init y), 1=L0 x-features, 2=L0 y-features, 3=hidden weights
  if (t == 0)      { c0 = 0;   nch = 64;  ci0 = 0; type = 0; fl = false; }
  else if (t == 1) { c0 = 64;  nch = 128; ci0 = 0; type = 1; fl = false; }
  else if (t == 2) { c0 = 192; nch = 128; ci0 = 2; type = 2; fl = true; }
  else {
    const int u = t - 3, l = u / 33, r = u - l * 33;
    if (r == 0) { c0 = 320 + l * 4160; nch = 64; ci0 = 0; type = 0; fl = false; }
    else {
      c0 = 384 + l * 4160 + (r - 1) * 128; nch = 128; ci0 = (r - 1) * 2;
      type = 3; fl = (r == 32);
    }
  }
}

__global__ __launch_bounds__(256, 2) void pqn(const float* __restrict__ lr,
                                              float* __restrict__ out) {
  __shared__ alignas(16) float A[2 * AHI];        // 65536 B (lo + hi planes)
  __shared__ alignas(16) float WB[2][4 * WROW];   // 4224 B

  const int tid = threadIdx.x;
  const int j   = tid & 3;
  const int pg  = (tid >> 2) & 7;      // pixel row (dy)
  const int cob = tid >> 5;            // 0..7

  // ---- swizzle: 4 siblings (same XCD) cover one 64B weight line
  const int n  = blockIdx.x;
  const int e2 = (n >> 3) & 3;
  const int P  = (n & 7) | ((n >> 5) << 3);   // 0..511
  const int jg = ((P & 3) << 2) | e2;         // 0..15 (4-j group)
  const int i  = (P >> 2) & 63;
  const int b  = (P >> 8) & 1;

  const float* __restrict__ wb =
      lr + (size_t)b * NPAR * PLANE + (size_t)(i * 64 + jg * 4);

  float fyc, fys;
  sincosf(0.78539816339744830962f * pg, &fys, &fyc);

  const int abase = pg * 16 + j * 4;   // == (lane&31)*4 : lane-contiguous
  const int wrow  = j * WROW;

  float y[64];                         // [col 0..7][k 0..7]

  auto compute = [&](int t, int bufsel) {
    int c0, nch, ci0, type; bool fl;
    tile_desc(t, c0, nch, ci0, type, fl);
    const float* Wt = WB[bufsel];
    if (type == 0) {                   // bias: init accumulators
#pragma unroll
      for (int q = 0; q < 2; ++q) {
        const float4 w = *(const float4*)&Wt[wrow + cob * 8 + q * 4];
#pragma unroll
        for (int m = 0; m < 4; ++m) {
          const float v = ((const float*)&w)[m];
#pragma unroll
          for (int k = 0; k < 8; ++k) y[(q * 4 + m) * 8 + k] = v;
        }
      }
    } else if (type == 1) {            // L0 x-features (compile-time a)
#pragma unroll
      for (int cl = 0; cl < 2; ++cl) {
#pragma unroll
        for (int q = 0; q < 2; ++q) {
          const float4 w = *(const float4*)&Wt[wrow + cl * 64 + cob * 8 + q * 4];
#pragma unroll
          for (int m = 0; m < 4; ++m) {
            const float wv = ((const float*)&w)[m];
            const int col = q * 4 + m;
#pragma unroll
            for (int k = 0; k < 8; ++k)
              y[col * 8 + k] = fmaf(cl ? sx(k) : cx(k), wv, y[col * 8 + k]);
          }
        }
      }
    } else if (type == 2) {            // L0 y-features (uniform over k)
#pragma unroll
      for (int cl = 0; cl < 2; ++cl) {
        const float a = cl ? fys : fyc;
#pragma unroll
        for (int q = 0; q < 2; ++q) {
          const float4 w = *(const float4*)&Wt[wrow + cl * 64 + cob * 8 + q * 4];
#pragma unroll
          for (int m = 0; m < 4; ++m) {
            const float wv = ((const float*)&w)[m];
            const int col = q * 4 + m;
#pragma unroll
            for (int k = 0; k < 8; ++k)
              y[col * 8 + k] = fmaf(a, wv, y[col * 8 + k]);
          }
        }
      }
    } else {                           // hidden: 2 ci per tile
#pragma unroll
      for (int cl = 0; cl < 2; ++cl) {
        const int ci = ci0 + cl;
        const float4 a0 = *(const float4*)&A[ci * 128 + abase];         // k0..3
        const float4 a1 = *(const float4*)&A[ci * 128 + abase + AHI];   // k4..7
#pragma unroll
        for (int q = 0; q < 2; ++q) {
          const float4 w = *(const float4*)&Wt[wrow + cl * 64 + cob * 8 + q * 4];
#pragma unroll
          for (int m = 0; m < 4; ++m) {
            const float wv = ((const float*)&w)[m];
            const int col = q * 4 + m;
            y[col * 8 + 0] = fmaf(a0.x, wv, y[col * 8 + 0]);
            y[col * 8 + 1] = fmaf(a0.y, wv, y[col * 8 + 1]);
            y[col * 8 + 2] = fmaf(a0.z, wv, y[col * 8 + 2]);
            y[col * 8 + 3] = fmaf(a0.w, wv, y[col * 8 + 3]);
            y[col * 8 + 4] = fmaf(a1.x, wv, y[col * 8 + 4]);
            y[col * 8 + 5] = fmaf(a1.y, wv, y[col * 8 + 5]);
            y[col * 8 + 6] = fmaf(a1.z, wv, y[col * 8 + 6]);
            y[col * 8 + 7] = fmaf(a1.w, wv, y[col * 8 + 7]);
          }
        }
      }
    }
    if (fl) {                          // layer end: publish activations
      asm volatile("s_waitcnt lgkmcnt(0)" ::: "memory");
      __builtin_amdgcn_s_barrier();    // everyone's A-reads done
      __builtin_amdgcn_sched_barrier(0);
#pragma unroll
      for (int col = 0; col < 8; ++col) {
        float4 v0, v1;
        v0.x = leaky(y[col * 8 + 0]); v0.y = leaky(y[col * 8 + 1]);
        v0.z = leaky(y[col * 8 + 2]); v0.w = leaky(y[col * 8 + 3]);
        v1.x = leaky(y[col * 8 + 4]); v1.y = leaky(y[col * 8 + 5]);
        v1.z = leaky(y[col * 8 + 6]); v1.w = leaky(y[col * 8 + 7]);
        *(float4*)&A[(cob * 8 + col) * 128 + abase]       = v0;
        *(float4*)&A[(cob * 8 + col) * 128 + abase + AHI] = v1;
      }
    }
  };

  // ---- prologue: 2-deep prefetch
  float4 stgA = {}, stgB = {};
  {
    int c0, nch, ci0, type; bool fl;
    tile_desc(0, c0, nch, ci0, type, fl);
    if (tid < nch) stgA = *(const float4*)(wb + (size_t)(c0 + tid) * PLANE);
    tile_desc(1, c0, nch, ci0, type, fl);
    if (tid < nch) stgB = *(const float4*)(wb + (size_t)(c0 + tid) * PLANE);
  }

  for (int t = 0; t < NT; t += 2) {
    // ---- phase A: tile t -> buf 0
    {
      int c0, nch, ci0, type; bool fl; tile_desc(t, c0, nch, ci0, type, fl);
      if (tid < nch) {
#pragma unroll
        for (int jj = 0; jj < 4; ++jj)
          WB[0][jj * WROW + tid] = ((const float*)&stgA)[jj];
      }
    }
    asm volatile("s_waitcnt lgkmcnt(0)" ::: "memory");
    __builtin_amdgcn_s_barrier();
    __builtin_amdgcn_sched_barrier(0);
    if (t + 2 < NT) {
      int c0, nch, ci0, type; bool fl; tile_desc(t + 2, c0, nch, ci0, type, fl);
      if (tid < nch) stgA = *(const float4*)(wb + (size_t)(c0 + tid) * PLANE);
    }
    compute(t, 0);
    // ---- phase B: tile t+1 -> buf 1
    {
      int c0, nch, ci0, type; bool fl; tile_desc(t + 1, c0, nch, ci0, type, fl);
      if (tid < nch) {
#pragma unroll
        for (int jj = 0; jj < 4; ++jj)
          WB[1][jj * WROW + tid] = ((const float*)&stgB)[jj];
      }
    }
    asm volatile("s_waitcnt lgkmcnt(0)" ::: "memory");
    __builtin_amdgcn_s_barrier();
    __builtin_amdgcn_sched_barrier(0);
    if (t + 3 < NT) {
      int c0, nch, ci0, type; bool fl; tile_desc(t + 3, c0, nch, ci0, type, fl);
      if (tid < nch) stgB = *(const float4*)(wb + (size_t)(c0 + tid) * PLANE);
    }
    compute(t + 1, 1);
  }

  // ---- epilogue: L4 (64 -> 3) + tanh
  asm volatile("s_waitcnt lgkmcnt(0)" ::: "memory");
  __builtin_amdgcn_s_barrier();
  __builtin_amdgcn_sched_barrier(0);

  float po[24];
#pragma unroll
  for (int m = 0; m < 24; ++m) po[m] = 0.f;
#pragma unroll
  for (int cl = 0; cl < 8; ++cl) {
    const int ci = cob * 8 + cl;
    const float4 a0 = *(const float4*)&A[ci * 128 + abase];
    const float4 a1 = *(const float4*)&A[ci * 128 + abase + AHI];
#pragma unroll
    for (int o = 0; o < 3; ++o) {
      const float w = wb[(size_t)(12803 + ci * 3 + o) * PLANE + j];
      po[o * 8 + 0] = fmaf(a0.x, w, po[o * 8 + 0]);
      po[o * 8 + 1] = fmaf(a0.y, w, po[o * 8 + 1]);
      po[o * 8 + 2] = fmaf(a0.z, w, po[o * 8 + 2]);
      po[o * 8 + 3] = fmaf(a0.w, w, po[o * 8 + 3]);
      po[o * 8 + 4] = fmaf(a1.x, w, po[o * 8 + 4]);
      po[o * 8 + 5] = fmaf(a1.y, w, po[o * 8 + 5]);
      po[o * 8 + 6] = fmaf(a1.z, w, po[o * 8 + 6]);
      po[o * 8 + 7] = fmaf(a1.w, w, po[o * 8 + 7]);
    }
  }
  asm volatile("s_waitcnt lgkmcnt(0)" ::: "memory");
  __builtin_amdgcn_s_barrier();        // all A reads done -> reuse A
  float* R = A;
#pragma unroll
  for (int m = 0; m < 24; m += 4)
    *(float4*)&R[tid * 28 + m] = *(float4*)&po[m];
  asm volatile("s_waitcnt lgkmcnt(0)" ::: "memory");
  __builtin_amdgcn_s_barrier();
  __builtin_amdgcn_sched_barrier(0);

  if (cob == 0) {                      // tid < 32: one (j, pg) per thread
#pragma unroll
    for (int o = 0; o < 3; ++o) {
      const float bias = wb[(size_t)(12800 + o) * PLANE + j];
      float s[8];
#pragma unroll
      for (int k = 0; k < 8; ++k) s[k] = bias;
#pragma unroll
      for (int cb = 0; cb < 8; ++cb) {
#pragma unroll
        for (int k = 0; k < 8; ++k)
          s[k] += R[(cb * 32 + tid) * 28 + o * 8 + k];
      }
      float4 v0, v1;
      v0.x = tanhf(s[0]); v0.y = tanhf(s[1]); v0.z = tanhf(s[2]); v0.w = tanhf(s[3]);
      v1.x = tanhf(s[4]); v1.y = tanhf(s[5]); v1.z = tanhf(s[6]); v1.w = tanhf(s[7]);
      float* op = out + (size_t)b * 786432 + (size_t)o * 262144 +
                  (size_t)(i * 8 + pg) * 512 + (size_t)((jg * 4 + j) * 8);
      *(float4*)op = v0;
      *(float4*)(op + 4) = v1;
    }
  }
}

extern "C" void kernel_launch(void* const* d_in, const int* in_sizes, int n_in,
                              void* d_out, int out_size, void* d_ws, size_t ws_size,
                              hipStream_t stream) {
  (void)in_sizes; (void)n_in; (void)d_ws; (void)ws_size; (void)out_size;
  const float* lr = (const float*)d_in[1];  // d_in[0] = highres (unused by the math)
  float* out = (float*)d_out;
  hipLaunchKernelGGL(pqn, dim3(2048), dim3(256), 0, stream, lr, out);
}